// Round 12
// baseline (523.826 us; speedup 1.0000x reference)
//
#include <hip/hip_runtime.h>
#include <math.h>

// Problem constants
#define BB   4
#define LL   4096          // H*W
#define L2T  8192          // 2*L (modality-interleaved sequence)
#define DM   96            // D_MODEL
#define CI   192           // D_INNER
#define KD   4             // K directions
#define NN   16            // D_STATE
#define RR   6             // DT_RANK
#define BKT  16            // B*K
#define SS   128           // scan segments
#define TT   64            // steps per segment = L2T/SS
#define DBLS 40            // padded row stride for x_dbl (38 -> 40 for float4)

// Workspace layout (float offsets) — identical to R9/R11 (proven passing incl. post-timing)
#define OFF_XPRE1 0
#define OFF_XPRE2 3145728
#define OFF_Z1    6291456
#define OFF_Z2    9437184
#define OFF_X1C   12582912
#define OFF_X2C   15728640
#define OFF_DBL   18874368   // BKT*L2T*40 = 5242880
#define OFF_MERG  24117248   // B*L*2*CI = 6291456 == SS*BKT*CI*NN (hend fits exactly)
#define OFF_DSUM  30408704   // SS*BKT*CI = 393216

template<int V> struct ic { static constexpr int value = V; };

// ---------------- in_proj: LDS-tiled GEMM. M=16384, N=384 (4 tiles of 96), K=96 ----------------
__global__ __launch_bounds__(256)
void k_inproj(const float* __restrict__ rgb, const float* __restrict__ tin,
              const float* __restrict__ w1, const float* __restrict__ w2,
              float* __restrict__ xp1, float* __restrict__ xp2,
              float* __restrict__ zz1, float* __restrict__ zz2) {
  int mb = blockIdx.x;     // row tile
  int nb = blockIdx.y;     // col tile (0..3)
  int m  = blockIdx.z;     // modality
  const float* in = m ? tin : rgb;
  const float* w  = (m ? w2 : w1) + nb * 96 * DM;
  __shared__ float As[64][100];
  __shared__ float Ws[96][98];
  int t = threadIdx.x;
  const float4* asrc = (const float4*)(in + (size_t)mb * 64 * DM);
  for (int i = t; i < 1536; i += 256) {
    int r = i / 24, kk = (i % 24) * 4;
    *(float4*)&As[r][kk] = asrc[i];
  }
  const float2* wsrc = (const float2*)w;
  for (int i = t; i < 4608; i += 256) {
    int r = i / 48, kk = (i % 48) * 2;
    *(float2*)&Ws[r][kk] = wsrc[i];
  }
  __syncthreads();
  int tc = t & 15, tr = t >> 4;
  float acc[4][6] = {};
  for (int k = 0; k < 96; k += 2) {
    float2 a[4], b[6];
#pragma unroll
    for (int i = 0; i < 4; i++) a[i] = *(const float2*)&As[tr * 4 + i][k];
#pragma unroll
    for (int j = 0; j < 6; j++) b[j] = *(const float2*)&Ws[tc * 6 + j][k];
#pragma unroll
    for (int i = 0; i < 4; i++)
#pragma unroll
      for (int j = 0; j < 6; j++) {
        acc[i][j] = fmaf(a[i].x, b[j].x, acc[i][j]);
        acc[i][j] = fmaf(a[i].y, b[j].y, acc[i][j]);
      }
  }
  float* dst = (nb < 2) ? (m ? xp2 : xp1) : (m ? zz2 : zz1);
  int colbase = (nb & 1) * 96 + tc * 6;
#pragma unroll
  for (int i = 0; i < 4; i++) {
    size_t bl = (size_t)mb * 64 + tr * 4 + i;
#pragma unroll
    for (int j = 0; j < 6; j++)
      dst[bl * CI + colbase + j] = acc[i][j];
  }
}

// ---------------- depthwise 3x3 conv (SAME, zero pad) + bias + SiLU ----------------
__global__ __launch_bounds__(256)
void k_conv(const float* __restrict__ xp1, const float* __restrict__ xp2,
            const float* __restrict__ c1w, const float* __restrict__ c1b,
            const float* __restrict__ c2w, const float* __restrict__ c2b,
            float* __restrict__ o1, float* __restrict__ o2) {
  int m = blockIdx.y;
  const float* in = m ? xp2 : xp1;
  const float* cw = m ? c2w : c1w;
  const float* cb = m ? c2b : c1b;
  float* out = m ? o2 : o1;
  int idx = blockIdx.x * 256 + threadIdx.x;
  int c = idx % CI;
  int bl = idx / CI;
  int b = bl / LL, l = bl % LL;
  int hh = l >> 6, ww = l & 63;
  float a = cb[c];
#pragma unroll
  for (int di = 0; di < 3; di++) {
    int h2 = hh + di - 1;
    if ((unsigned)h2 >= 64u) continue;
#pragma unroll
    for (int dj = 0; dj < 3; dj++) {
      int w2 = ww + dj - 1;
      if ((unsigned)w2 >= 64u) continue;
      a = fmaf(in[(b * LL + h2 * 64 + w2) * CI + c], cw[c * 9 + di * 3 + dj], a);
    }
  }
  out[idx] = a / (1.f + __expf(-a));
}

// ---------------- x_dbl projection as tiled GEMM per (b,k) ----------------
__global__ __launch_bounds__(256)
void k_dbl(const float* __restrict__ x1c, const float* __restrict__ x2c,
           const float* __restrict__ wx, float* __restrict__ dbl) {
  int pt = blockIdx.x;
  int bk = blockIdx.y;
  int b = bk >> 2, k = bk & 3;
  __shared__ float As[64][100];
  __shared__ float Ws[40][100];
  int t = threadIdx.x;
  int tc = t & 7, tr = t >> 3;
  float acc[2][5] = {};
  for (int kc = 0; kc < 2; kc++) {
    if (kc) __syncthreads();
    for (int i = t; i < 1536; i += 256) {
      int r = i / 24, kk = (i % 24) * 4;
      int l2 = pt * 64 + r;
      int mm = l2 & 1, l = l2 >> 1;
      int lt = (k >= 2) ? (LL - 1 - l) : l;
      int sp = (k & 1) ? (((lt & 63) << 6) | (lt >> 6)) : lt;
      const float* src = (mm ? x2c : x1c) + ((size_t)(b * LL + sp)) * CI + kc * 96;
      *(float4*)&As[r][kk] = *(const float4*)(src + kk);
    }
    for (int i = t; i < 960; i += 256) {
      int r = i / 24, kk = (i % 24) * 4;
      float4 v;
      if (r < 38) v = *(const float4*)&wx[(size_t)(k * 38 + r) * CI + kc * 96 + kk];
      else        v = float4{0.f, 0.f, 0.f, 0.f};
      *(float4*)&Ws[r][kk] = v;
    }
    __syncthreads();
    for (int kk2 = 0; kk2 < 96; kk2 += 2) {
      float2 a[2], bv[5];
#pragma unroll
      for (int i = 0; i < 2; i++) a[i] = *(const float2*)&As[tr * 2 + i][kk2];
#pragma unroll
      for (int j = 0; j < 5; j++) bv[j] = *(const float2*)&Ws[tc * 5 + j][kk2];
#pragma unroll
      for (int i = 0; i < 2; i++)
#pragma unroll
        for (int j = 0; j < 5; j++) {
          acc[i][j] = fmaf(a[i].x, bv[j].x, acc[i][j]);
          acc[i][j] = fmaf(a[i].y, bv[j].y, acc[i][j]);
        }
    }
  }
#pragma unroll
  for (int i = 0; i < 2; i++) {
    size_t row = (size_t)bk * L2T + pt * 64 + tr * 2 + i;
#pragma unroll
    for (int j = 0; j < 5; j++) {
      int cc = tc * 5 + j;
      if (cc < 38) dbl[row * DBLS + cc] = acc[i][j];
    }
  }
}

// ---------------- segmented selective scan: 384-thread blocks, state-split ----------------
// Block = one (bk,s): 6 waves = {2 state-halves} x {3 c-groups}. Row pointer depends only on
// blockIdx -> block-uniform -> s_load scalarization preserved; all 6 waves share K$ rows.
// Each wave owns 8 states [NB0, NB0+8). Pass1: halves write disjoint hend slices, half0 writes
// dsum. Pass2: partial y via atomic merge (u*Dv added by half0 only).
template<int PASS>
__global__ __launch_bounds__(384)
void k_scan(const float* __restrict__ x1c, const float* __restrict__ x2c,
            const float* __restrict__ dbl,
            const float* __restrict__ dtw, const float* __restrict__ dtb,
            const float* __restrict__ alogs, const float* __restrict__ dsv,
            float* __restrict__ hend, float* __restrict__ dsum,
            const float* __restrict__ hin, float* __restrict__ merged) {
  int bid = blockIdx.x;          // SS*BKT = 2048
  int s  = bid & (SS - 1);
  int bk = bid >> 7;             // 0..15
  int b = bk >> 2, kdir = bk & 3;
  int tid = threadIdx.x;         // 0..383
  int half = tid / 192;          // wave-uniform
  int c = tid % 192;
  int kc = kdir * CI + c;

  float w2r0 = dtw[kc * RR + 0], w2r1 = dtw[kc * RR + 1], w2r2 = dtw[kc * RR + 2];
  float w2r3 = dtw[kc * RR + 3], w2r4 = dtw[kc * RR + 4], w2r5 = dtw[kc * RR + 5];
  float bias = dtb[kc];
  float Dv   = (PASS == 2 && half == 0) ? dsv[kc] : 0.f;
  float a16[NN];
#pragma unroll
  for (int n = 0; n < NN; n++) a16[n] = -__expf(alogs[kc * NN + n]);
  float A1 = a16[0];
  int ok = 1;
#pragma unroll
  for (int n = 1; n < NN; n++) {
    float want = A1 * (float)(n + 1);
    if (!(fabsf(a16[n] - want) <= fabsf(want) * 1e-3f + 1e-6f)) ok = 0;
  }
  const bool structured = (__all(ok) != 0);   // A[n] = (n+1)*A1 -> dA[n] = r^(n+1)

  const float4* dp4 = (const float4*)(dbl + (size_t)(bk * L2T + s * TT) * DBLS);  // block-uniform
  const float* u1b = x1c + (size_t)b * LL * CI + c;
  const float* u2b = x2c + (size_t)b * LL * CI + c;

  auto spmap = [&](int l) -> int {
    int lt = (kdir >= 2) ? (LL - 1 - l) : l;
    return (kdir & 1) ? (((lt & 63) << 6) | (lt >> 6)) : lt;
  };

  // load one step's row (40 floats = 10 quads; pass1 needs only dt_r+B = first 6)
  auto loadrow = [&](float4* Q, int t) {
    const float4* r4 = dp4 + t * 10;
    Q[0] = r4[0]; Q[1] = r4[1]; Q[2] = r4[2];
    Q[3] = r4[3]; Q[4] = r4[4]; Q[5] = r4[5];
    if (PASS == 2) { Q[6] = r4[6]; Q[7] = r4[7]; Q[8] = r4[8]; Q[9] = r4[9]; }
  };

#define DG(Q, i) ((i & 3) == 0 ? Q[(i) >> 2].x : (i & 3) == 1 ? Q[(i) >> 2].y : (i & 3) == 2 ? Q[(i) >> 2].z : Q[(i) >> 2].w)

  auto run = [&](auto nb0c) {
    constexpr int NB0 = decltype(nb0c)::value;
    float Areg[8];
#pragma unroll
    for (int j = 0; j < 8; j++) Areg[j] = a16[NB0 + j];
    float h[8];
    if (PASS == 2) {
      int base = ((s * BKT + bk) * CI + c) * NN + NB0;
#pragma unroll
      for (int j = 0; j < 8; j++) h[j] = hin[base + j];
    } else {
#pragma unroll
      for (int j = 0; j < 8; j++) h[j] = 0.f;
    }
    float dacc = 0.f;

    // one scan step from register quads Q[0..9]
    auto step = [&](const float4* Q, float u, float& y) {
      float x = bias;
      x = fmaf(DG(Q, 0), w2r0, x); x = fmaf(DG(Q, 1), w2r1, x); x = fmaf(DG(Q, 2), w2r2, x);
      x = fmaf(DG(Q, 3), w2r3, x); x = fmaf(DG(Q, 4), w2r4, x); x = fmaf(DG(Q, 5), w2r5, x);
      float delta = (x > 15.f) ? x : __logf(1.f + __expf(x));
      float du = delta * u;
      float y0 = 0.f, y1 = 0.f;
      if (structured) {
        float r  = __expf(delta * A1);
        float r2 = r * r, r3 = r2 * r, r4 = r2 * r2;
        float r5 = r4 * r, r6 = r4 * r2, r7 = r4 * r3, r8 = r4 * r4;
        float pw[8];
        if constexpr (NB0 == 0) {
          pw[0] = r;  pw[1] = r2; pw[2] = r3; pw[3] = r4;
          pw[4] = r5; pw[5] = r6; pw[6] = r7; pw[7] = r8;
        } else {
          pw[0] = r8 * r;  pw[1] = r8 * r2; pw[2] = r8 * r3; pw[3] = r8 * r4;
          pw[4] = r8 * r5; pw[5] = r8 * r6; pw[6] = r8 * r7; pw[7] = r8 * r8;
        }
#pragma unroll
        for (int j = 0; j < 8; j++) {
          h[j] = fmaf(h[j], pw[j], du * DG(Q, 6 + NB0 + j));
          if (PASS == 2) {
            if (j & 1) y1 = fmaf(h[j], DG(Q, 22 + NB0 + j), y1);
            else       y0 = fmaf(h[j], DG(Q, 22 + NB0 + j), y0);
          }
        }
      } else {
#pragma unroll
        for (int j = 0; j < 8; j++) {
          float dA = __expf(delta * Areg[j]);
          h[j] = fmaf(h[j], dA, du * DG(Q, 6 + NB0 + j));
          if (PASS == 2) {
            if (j & 1) y1 = fmaf(h[j], DG(Q, 22 + NB0 + j), y1);
            else       y0 = fmaf(h[j], DG(Q, 22 + NB0 + j), y0);
          }
        }
      }
      if (PASS == 1) dacc += delta;
      else y = fmaf(u, Dv, y0 + y1);
    };

    int l0 = (s * TT) >> 1;
    float4 qA[10], qB[10];
    int spC = spmap(l0);
    float u1C = u1b[(size_t)spC * CI];
    float u2C = u2b[(size_t)spC * CI];
    loadrow(qA, 0);
    int spN = 0; float u1N = 0.f, u2N = 0.f;
#pragma unroll 1
    for (int t = 0; t < TT; t += 2) {
      loadrow(qB, t + 1);                       // odd row, used after even step
      if (t + 2 < TT) {                         // next pair's u (2 steps of slack)
        spN = spmap(l0 + (t >> 1) + 1);
        u1N = u1b[(size_t)spN * CI];
        u2N = u2b[(size_t)spN * CI];
      }
      float ya, yb;
      step(qA, u1C, ya);                        // even step: modality rgb (m=0)
      if (t + 2 < TT) loadrow(qA, t + 2);       // next even row (1.5 steps of slack)
      step(qB, u2C, yb);                        // odd step: modality t (m=1)
      if (PASS == 2) {
        float* mrow = merged + (size_t)(b * LL + spC) * (2 * CI) + c;
        atomicAdd(mrow, ya);
        atomicAdd(mrow + CI, yb);
      }
      spC = spN; u1C = u1N; u2C = u2N;
    }

    if (PASS == 1) {
      int base = ((s * BKT + bk) * CI + c) * NN + NB0;
#pragma unroll
      for (int j = 0; j < 8; j++) hend[base + j] = h[j];
      if constexpr (NB0 == 0) {
        dsum[(s * BKT + bk) * CI + c] = dacc;
      }
    }
  };

  if (half == 0) run(ic<0>{});
  else           run(ic<8>{});
#undef DG
}

// ---------------- propagate segment initial states (two-buffer) ----------------
__global__ __launch_bounds__(256)
void k_prop(const float* __restrict__ hend, const float* __restrict__ dsum,
            const float* __restrict__ alogs, float* __restrict__ hin) {
  int idx = blockIdx.x * 256 + threadIdx.x;   // BKT*CI*NN = 49152
  int n = idx & 15;
  int rest = idx >> 4;
  int c = rest % CI;
  int bk = rest / CI;
  int k = bk & 3;
  float A = -__expf(alogs[(k * CI + c) * NN + n]);
  float h = 0.f;
  for (int s = 0; s < SS; s++) {
    int cell = (s * BKT + bk) * CI + c;
    hin[cell * NN + n] = h;
    float ap = __expf(A * dsum[cell]);
    h = h * ap + hend[cell * NN + n];
  }
}

// ---------------- LayerNorm over CI + SiLU(z) gate (in-place on merged) ----------------
__global__ __launch_bounds__(192)
void k_lngate(float* __restrict__ merged,
              const float* __restrict__ z1, const float* __restrict__ z2,
              const float* __restrict__ n1w, const float* __restrict__ n1b,
              const float* __restrict__ n2w, const float* __restrict__ n2b) {
  int bid = blockIdx.x;
  int m = bid & 1;
  int bl = bid >> 1;
  int c = threadIdx.x;
  float v = merged[(size_t)bid * CI + c];
  float s1 = v, s2 = v * v;
  for (int o = 32; o > 0; o >>= 1) {
    s1 += __shfl_xor(s1, o);
    s2 += __shfl_xor(s2, o);
  }
  __shared__ float red[2][3];
  int wv = threadIdx.x >> 6, ln = threadIdx.x & 63;
  if (ln == 0) { red[0][wv] = s1; red[1][wv] = s2; }
  __syncthreads();
  float S1 = red[0][0] + red[0][1] + red[0][2];
  float S2 = red[1][0] + red[1][1] + red[1][2];
  float mean = S1 * (1.f / CI);
  float var = S2 * (1.f / CI) - mean * mean;
  float rstd = rsqrtf(var + 1e-5f);
  const float* nw = m ? n2w : n1w;
  const float* nb = m ? n2b : n1b;
  float vn = (v - mean) * rstd * nw[c] + nb[c];
  float z = (m ? z2 : z1)[(size_t)bl * CI + c];
  float g = vn * (z / (1.f + __expf(-z)));
  merged[(size_t)bid * CI + c] = g;
}

// ---------------- out_proj: LDS-tiled GEMM. M=16384, N=96, K=192 (2 chunks) ----------------
__global__ __launch_bounds__(256)
void k_outproj(const float* __restrict__ g,
               const float* __restrict__ w1, const float* __restrict__ w2,
               float* __restrict__ out) {
  int mb = blockIdx.x;
  int m  = blockIdx.y;
  const float* w = m ? w2 : w1;
  __shared__ float As[64][100];
  __shared__ float Ws[96][98];
  int t = threadIdx.x;
  int tc = t & 15, tr = t >> 4;
  float acc[4][6] = {};
  for (int kc = 0; kc < 2; kc++) {
    if (kc) __syncthreads();
    for (int i = t; i < 1536; i += 256) {
      int r = i / 24, kk = (i % 24) * 4;
      *(float4*)&As[r][kk] =
          *(const float4*)&g[((size_t)(mb * 64 + r) * 2 + m) * CI + kc * 96 + kk];
    }
    for (int i = t; i < 4608; i += 256) {
      int r = i / 48, kk = (i % 48) * 2;
      *(float2*)&Ws[r][kk] = *(const float2*)&w[(size_t)r * CI + kc * 96 + kk];
    }
    __syncthreads();
    for (int k = 0; k < 96; k += 2) {
      float2 a[4], b[6];
#pragma unroll
      for (int i = 0; i < 4; i++) a[i] = *(const float2*)&As[tr * 4 + i][k];
#pragma unroll
      for (int j = 0; j < 6; j++) b[j] = *(const float2*)&Ws[tc * 6 + j][k];
#pragma unroll
      for (int i = 0; i < 4; i++)
#pragma unroll
        for (int j = 0; j < 6; j++) {
          acc[i][j] = fmaf(a[i].x, b[j].x, acc[i][j]);
          acc[i][j] = fmaf(a[i].y, b[j].y, acc[i][j]);
        }
    }
  }
  float* outp = out + (size_t)m * (BB * LL * DM);
#pragma unroll
  for (int i = 0; i < 4; i++) {
    size_t bl = (size_t)mb * 64 + tr * 4 + i;
#pragma unroll
    for (int j = 0; j < 6; j++)
      outp[bl * DM + tc * 6 + j] = acc[i][j];
  }
}

extern "C" void kernel_launch(void* const* d_in, const int* in_sizes, int n_in,
                              void* d_out, int out_size, void* d_ws, size_t ws_size,
                              hipStream_t stream) {
  const float* rgb = (const float*)d_in[0];
  const float* tin = (const float*)d_in[1];
  const float* ip1 = (const float*)d_in[2];
  const float* ip2 = (const float*)d_in[3];
  const float* c1w = (const float*)d_in[4];
  const float* c1b = (const float*)d_in[5];
  const float* c2w = (const float*)d_in[6];
  const float* c2b = (const float*)d_in[7];
  const float* wx  = (const float*)d_in[8];
  const float* dtw = (const float*)d_in[9];
  const float* dtb = (const float*)d_in[10];
  const float* alg = (const float*)d_in[11];
  const float* Dsp = (const float*)d_in[12];
  const float* n1w = (const float*)d_in[13];
  const float* n1b = (const float*)d_in[14];
  const float* n2w = (const float*)d_in[15];
  const float* n2b = (const float*)d_in[16];
  const float* op1 = (const float*)d_in[17];
  const float* op2 = (const float*)d_in[18];

  float* ws = (float*)d_ws;
  float* xp1 = ws + OFF_XPRE1;
  float* xp2 = ws + OFF_XPRE2;
  float* z1  = ws + OFF_Z1;
  float* z2  = ws + OFF_Z2;
  float* x1c = ws + OFF_X1C;
  float* x2c = ws + OFF_X2C;
  float* dbl = ws + OFF_DBL;
  float* mg  = ws + OFF_MERG;
  float* dsm = ws + OFF_DSUM;
  // hend lives in the mg region (pass1 -> prop only; memset erases it afterwards).
  // hin spans xp1+xp2 (dead after k_conv): SS*BKT*CI*NN = 6291456 floats, exact fit.
  float* he  = ws + OFF_MERG;
  float* hi  = ws + OFF_XPRE1;
  float* out = (float*)d_out;

  k_inproj<<<dim3(256, 4, 2), 256, 0, stream>>>(rgb, tin, ip1, ip2, xp1, xp2, z1, z2);
  k_conv<<<dim3(12288, 2), 256, 0, stream>>>(xp1, xp2, c1w, c1b, c2w, c2b, x1c, x2c);
  k_dbl<<<dim3(128, 16), 256, 0, stream>>>(x1c, x2c, wx, dbl);
  k_scan<1><<<SS * BKT, 384, 0, stream>>>(x1c, x2c, dbl, dtw, dtb, alg, Dsp, he, dsm, hi, mg);
  k_prop<<<192, 256, 0, stream>>>(he, dsm, alg, hi);
  // zero the merge accumulator only now (hend is dead after k_prop)
  hipMemsetAsync(mg, 0, (size_t)6291456 * sizeof(float), stream);
  k_scan<2><<<SS * BKT, 384, 0, stream>>>(x1c, x2c, dbl, dtw, dtb, alg, Dsp, he, dsm, hi, mg);
  k_lngate<<<BB * LL * 2, 192, 0, stream>>>(mg, z1, z2, n1w, n1b, n2w, n2b);
  k_outproj<<<dim3(256, 2), 256, 0, stream>>>(mg, op1, op2, out);
}

// Round 13
// 428.719 us; speedup vs baseline: 1.2218x; 1.2218x over previous
//
#include <hip/hip_runtime.h>
#include <math.h>

// Problem constants
#define BB   4
#define LL   4096          // H*W
#define L2T  8192          // 2*L (modality-interleaved sequence)
#define DM   96            // D_MODEL
#define CI   192           // D_INNER
#define KD   4             // K directions
#define NN   16            // D_STATE
#define RR   6             // DT_RANK
#define BKT  16            // B*K
#define SS   128           // scan segments
#define TT   64            // steps per segment = L2T/SS
#define DBLS 40            // padded row stride for x_dbl (38 -> 40 for float4)

// Workspace layout (float offsets) — identical to R9/R11 (proven passing incl. post-timing)
#define OFF_XPRE1 0
#define OFF_XPRE2 3145728
#define OFF_Z1    6291456
#define OFF_Z2    9437184
#define OFF_X1C   12582912
#define OFF_X2C   15728640
#define OFF_DBL   18874368   // BKT*L2T*40 = 5242880
#define OFF_MERG  24117248   // B*L*2*CI = 6291456 == SS*BKT*CI*NN (hend fits exactly)
#define OFF_DSUM  30408704   // SS*BKT*CI = 393216

// ---------------- in_proj: LDS-tiled GEMM. M=16384, N=384 (4 tiles of 96), K=96 ----------------
__global__ __launch_bounds__(256)
void k_inproj(const float* __restrict__ rgb, const float* __restrict__ tin,
              const float* __restrict__ w1, const float* __restrict__ w2,
              float* __restrict__ xp1, float* __restrict__ xp2,
              float* __restrict__ zz1, float* __restrict__ zz2) {
  int mb = blockIdx.x;     // row tile
  int nb = blockIdx.y;     // col tile (0..3)
  int m  = blockIdx.z;     // modality
  const float* in = m ? tin : rgb;
  const float* w  = (m ? w2 : w1) + nb * 96 * DM;
  __shared__ float As[64][100];
  __shared__ float Ws[96][98];
  int t = threadIdx.x;
  const float4* asrc = (const float4*)(in + (size_t)mb * 64 * DM);
  for (int i = t; i < 1536; i += 256) {
    int r = i / 24, kk = (i % 24) * 4;
    *(float4*)&As[r][kk] = asrc[i];
  }
  const float2* wsrc = (const float2*)w;
  for (int i = t; i < 4608; i += 256) {
    int r = i / 48, kk = (i % 48) * 2;
    *(float2*)&Ws[r][kk] = wsrc[i];
  }
  __syncthreads();
  int tc = t & 15, tr = t >> 4;
  float acc[4][6] = {};
  for (int k = 0; k < 96; k += 2) {
    float2 a[4], b[6];
#pragma unroll
    for (int i = 0; i < 4; i++) a[i] = *(const float2*)&As[tr * 4 + i][k];
#pragma unroll
    for (int j = 0; j < 6; j++) b[j] = *(const float2*)&Ws[tc * 6 + j][k];
#pragma unroll
    for (int i = 0; i < 4; i++)
#pragma unroll
      for (int j = 0; j < 6; j++) {
        acc[i][j] = fmaf(a[i].x, b[j].x, acc[i][j]);
        acc[i][j] = fmaf(a[i].y, b[j].y, acc[i][j]);
      }
  }
  float* dst = (nb < 2) ? (m ? xp2 : xp1) : (m ? zz2 : zz1);
  int colbase = (nb & 1) * 96 + tc * 6;
#pragma unroll
  for (int i = 0; i < 4; i++) {
    size_t bl = (size_t)mb * 64 + tr * 4 + i;
#pragma unroll
    for (int j = 0; j < 6; j++)
      dst[bl * CI + colbase + j] = acc[i][j];
  }
}

// ---------------- depthwise 3x3 conv (SAME, zero pad) + bias + SiLU ----------------
__global__ __launch_bounds__(256)
void k_conv(const float* __restrict__ xp1, const float* __restrict__ xp2,
            const float* __restrict__ c1w, const float* __restrict__ c1b,
            const float* __restrict__ c2w, const float* __restrict__ c2b,
            float* __restrict__ o1, float* __restrict__ o2) {
  int m = blockIdx.y;
  const float* in = m ? xp2 : xp1;
  const float* cw = m ? c2w : c1w;
  const float* cb = m ? c2b : c1b;
  float* out = m ? o2 : o1;
  int idx = blockIdx.x * 256 + threadIdx.x;
  int c = idx % CI;
  int bl = idx / CI;
  int b = bl / LL, l = bl % LL;
  int hh = l >> 6, ww = l & 63;
  float a = cb[c];
#pragma unroll
  for (int di = 0; di < 3; di++) {
    int h2 = hh + di - 1;
    if ((unsigned)h2 >= 64u) continue;
#pragma unroll
    for (int dj = 0; dj < 3; dj++) {
      int w2 = ww + dj - 1;
      if ((unsigned)w2 >= 64u) continue;
      a = fmaf(in[(b * LL + h2 * 64 + w2) * CI + c], cw[c * 9 + di * 3 + dj], a);
    }
  }
  out[idx] = a / (1.f + __expf(-a));
}

// ---------------- x_dbl projection as tiled GEMM per (b,k) ----------------
__global__ __launch_bounds__(256)
void k_dbl(const float* __restrict__ x1c, const float* __restrict__ x2c,
           const float* __restrict__ wx, float* __restrict__ dbl) {
  int pt = blockIdx.x;
  int bk = blockIdx.y;
  int b = bk >> 2, k = bk & 3;
  __shared__ float As[64][100];
  __shared__ float Ws[40][100];
  int t = threadIdx.x;
  int tc = t & 7, tr = t >> 3;
  float acc[2][5] = {};
  for (int kc = 0; kc < 2; kc++) {
    if (kc) __syncthreads();
    for (int i = t; i < 1536; i += 256) {
      int r = i / 24, kk = (i % 24) * 4;
      int l2 = pt * 64 + r;
      int mm = l2 & 1, l = l2 >> 1;
      int lt = (k >= 2) ? (LL - 1 - l) : l;
      int sp = (k & 1) ? (((lt & 63) << 6) | (lt >> 6)) : lt;
      const float* src = (mm ? x2c : x1c) + ((size_t)(b * LL + sp)) * CI + kc * 96;
      *(float4*)&As[r][kk] = *(const float4*)(src + kk);
    }
    for (int i = t; i < 960; i += 256) {
      int r = i / 24, kk = (i % 24) * 4;
      float4 v;
      if (r < 38) v = *(const float4*)&wx[(size_t)(k * 38 + r) * CI + kc * 96 + kk];
      else        v = float4{0.f, 0.f, 0.f, 0.f};
      *(float4*)&Ws[r][kk] = v;
    }
    __syncthreads();
    for (int kk2 = 0; kk2 < 96; kk2 += 2) {
      float2 a[2], bv[5];
#pragma unroll
      for (int i = 0; i < 2; i++) a[i] = *(const float2*)&As[tr * 2 + i][kk2];
#pragma unroll
      for (int j = 0; j < 5; j++) bv[j] = *(const float2*)&Ws[tc * 5 + j][kk2];
#pragma unroll
      for (int i = 0; i < 2; i++)
#pragma unroll
        for (int j = 0; j < 5; j++) {
          acc[i][j] = fmaf(a[i].x, bv[j].x, acc[i][j]);
          acc[i][j] = fmaf(a[i].y, bv[j].y, acc[i][j]);
        }
    }
  }
#pragma unroll
  for (int i = 0; i < 2; i++) {
    size_t row = (size_t)bk * L2T + pt * 64 + tr * 2 + i;
#pragma unroll
    for (int j = 0; j < 5; j++) {
      int cc = tc * 5 + j;
      if (cc < 38) dbl[row * DBLS + cc] = acc[i][j];
    }
  }
}

// ---------------- segmented selective scan: 192-thread blocks, deep u-prefetch ----------------
// R11 structure (block = 3 c-group waves of one (bk,s); block-uniform row pointer -> s_load
// scalarization + K$ sharing) + u prefetched 2 PAIRS ahead (named C/N/N2 regs, ~4 steps of
// slack) so the transposed directions' 49KB-stride u stream stops stalling each step.
template<int PASS>
__global__ __launch_bounds__(192)
void k_scan(const float* __restrict__ x1c, const float* __restrict__ x2c,
            const float* __restrict__ dbl,
            const float* __restrict__ dtw, const float* __restrict__ dtb,
            const float* __restrict__ alogs, const float* __restrict__ dsv,
            float* __restrict__ hend, float* __restrict__ dsum,
            const float* __restrict__ hin, float* __restrict__ merged) {
  int bid = blockIdx.x;          // SS*BKT
  int s  = bid & (SS - 1);
  int bk = bid >> 7;             // 0..15
  int b = bk >> 2, kdir = bk & 3;
  int c = threadIdx.x;           // 0..191 (wave w covers c in [w*64, w*64+64))
  int kc = kdir * CI + c;

  float w2r0 = dtw[kc * RR + 0], w2r1 = dtw[kc * RR + 1], w2r2 = dtw[kc * RR + 2];
  float w2r3 = dtw[kc * RR + 3], w2r4 = dtw[kc * RR + 4], w2r5 = dtw[kc * RR + 5];
  float bias = dtb[kc];
  float Dv   = (PASS == 2) ? dsv[kc] : 0.f;
  float Areg[NN];
#pragma unroll
  for (int n = 0; n < NN; n++) Areg[n] = -__expf(alogs[kc * NN + n]);
  float A1 = Areg[0];
  int ok = 1;
#pragma unroll
  for (int n = 1; n < NN; n++) {
    float want = A1 * (float)(n + 1);
    if (!(fabsf(Areg[n] - want) <= fabsf(want) * 1e-3f + 1e-6f)) ok = 0;
  }
  const bool structured = (__all(ok) != 0);   // A[n] = (n+1)*A1 -> dA[n] = r^(n+1)

  float h[NN];
  if (PASS == 2) {
    int base = ((s * BKT + bk) * CI + c) * NN;
#pragma unroll
    for (int n = 0; n < NN; n++) h[n] = hin[base + n];
  } else {
#pragma unroll
    for (int n = 0; n < NN; n++) h[n] = 0.f;
  }
  float dacc = 0.f;

  const float4* dp4 = (const float4*)(dbl + (size_t)(bk * L2T + s * TT) * DBLS);  // block-uniform
  const float* u1b = x1c + (size_t)b * LL * CI + c;
  const float* u2b = x2c + (size_t)b * LL * CI + c;

  auto spmap = [&](int l) -> int {
    int lt = (kdir >= 2) ? (LL - 1 - l) : l;
    return (kdir & 1) ? (((lt & 63) << 6) | (lt >> 6)) : lt;
  };

  // load one step's row (40 floats = 10 quads; pass1 needs only dt_r+B = first 6)
  auto loadrow = [&](float4* Q, int t) {
    const float4* r4 = dp4 + t * 10;
    Q[0] = r4[0]; Q[1] = r4[1]; Q[2] = r4[2];
    Q[3] = r4[3]; Q[4] = r4[4]; Q[5] = r4[5];
    if (PASS == 2) { Q[6] = r4[6]; Q[7] = r4[7]; Q[8] = r4[8]; Q[9] = r4[9]; }
  };

#define DG(Q, i) ((i & 3) == 0 ? Q[(i) >> 2].x : (i & 3) == 1 ? Q[(i) >> 2].y : (i & 3) == 2 ? Q[(i) >> 2].z : Q[(i) >> 2].w)

  // one scan step from register quads Q[0..9]
  auto step = [&](const float4* Q, float u, float& y) {
    float x = bias;
    x = fmaf(DG(Q, 0), w2r0, x); x = fmaf(DG(Q, 1), w2r1, x); x = fmaf(DG(Q, 2), w2r2, x);
    x = fmaf(DG(Q, 3), w2r3, x); x = fmaf(DG(Q, 4), w2r4, x); x = fmaf(DG(Q, 5), w2r5, x);
    float delta = (x > 15.f) ? x : __logf(1.f + __expf(x));
    float du = delta * u;
    float y0 = 0.f, y1 = 0.f, y2 = 0.f, y3 = 0.f;
    if (structured) {
      float r  = __expf(delta * A1);
      float r2 = r * r, r3 = r2 * r, r4 = r2 * r2;
      float r6 = r4 * r2, r8 = r4 * r4;
      float pw[NN];
      pw[0] = r;       pw[1] = r2;      pw[2] = r3;      pw[3] = r4;
      pw[4] = r4 * r;  pw[5] = r6;      pw[6] = r4 * r3; pw[7] = r8;
      pw[8] = r8 * r;  pw[9] = r8 * r2; pw[10] = r8 * r3; pw[11] = r8 * r4;
      pw[12] = r8 * pw[4]; pw[13] = r8 * r6; pw[14] = r8 * pw[6]; pw[15] = r8 * r8;
#pragma unroll
      for (int n = 0; n < NN; n++) {
        h[n] = fmaf(h[n], pw[n], du * DG(Q, 6 + n));
        if (PASS == 2) {
          float* yp = (n & 2) ? ((n & 1) ? &y3 : &y2) : ((n & 1) ? &y1 : &y0);
          *yp = fmaf(h[n], DG(Q, 22 + n), *yp);
        }
      }
    } else {
#pragma unroll
      for (int n = 0; n < NN; n++) {
        float dA = __expf(delta * Areg[n]);
        h[n] = fmaf(h[n], dA, du * DG(Q, 6 + n));
        if (PASS == 2) {
          float* yp = (n & 2) ? ((n & 1) ? &y3 : &y2) : ((n & 1) ? &y1 : &y0);
          *yp = fmaf(h[n], DG(Q, 22 + n), *yp);
        }
      }
    }
    if (PASS == 1) dacc += delta;
    else y = fmaf(u, Dv, (y0 + y1) + (y2 + y3));
  };

  const int NP = TT / 2;         // pairs
  int l0 = (s * TT) >> 1;
  float4 qA[10], qB[10];
  // prologue: u pipeline 3 deep (pairs 0,1,2), row for step 0
  int spC = spmap(l0);
  float u1C = u1b[(size_t)spC * CI];
  float u2C = u2b[(size_t)spC * CI];
  int spN = spmap(l0 + 1);
  float u1N = u1b[(size_t)spN * CI];
  float u2N = u2b[(size_t)spN * CI];
  int spN2 = spmap(l0 + 2);
  float u1N2 = u1b[(size_t)spN2 * CI];
  float u2N2 = u2b[(size_t)spN2 * CI];
  loadrow(qA, 0);
#pragma unroll 1
  for (int t = 0; t < TT; t += 2) {
    int p = t >> 1;
    loadrow(qB, t + 1);                       // odd row, used after even step
    // issue pair p+3's u loads (2 pairs of slack beyond the one being shifted in)
    int spN3 = 0; float u1N3 = 0.f, u2N3 = 0.f;
    if (p + 3 < NP) {
      spN3 = spmap(l0 + p + 3);
      u1N3 = u1b[(size_t)spN3 * CI];
      u2N3 = u2b[(size_t)spN3 * CI];
    }
    float ya, yb;
    step(qA, u1C, ya);                        // even step: modality rgb (m=0)
    if (t + 2 < TT) loadrow(qA, t + 2);       // next even row (1.5 steps of slack)
    step(qB, u2C, yb);                        // odd step: modality t (m=1)
    if (PASS == 2) {
      float* mrow = merged + (size_t)(b * LL + spC) * (2 * CI) + c;
      atomicAdd(mrow, ya);
      atomicAdd(mrow + CI, yb);
    }
    // shift the u pipeline
    spC = spN;  u1C = u1N;  u2C = u2N;
    spN = spN2; u1N = u1N2; u2N = u2N2;
    spN2 = spN3; u1N2 = u1N3; u2N2 = u2N3;
  }
#undef DG

  if (PASS == 1) {
    int base = ((s * BKT + bk) * CI + c) * NN;
#pragma unroll
    for (int n = 0; n < NN; n++) hend[base + n] = h[n];
    dsum[(s * BKT + bk) * CI + c] = dacc;
  }
}

// ---------------- propagate segment initial states (two-buffer) ----------------
__global__ __launch_bounds__(256)
void k_prop(const float* __restrict__ hend, const float* __restrict__ dsum,
            const float* __restrict__ alogs, float* __restrict__ hin) {
  int idx = blockIdx.x * 256 + threadIdx.x;   // BKT*CI*NN = 49152
  int n = idx & 15;
  int rest = idx >> 4;
  int c = rest % CI;
  int bk = rest / CI;
  int k = bk & 3;
  float A = -__expf(alogs[(k * CI + c) * NN + n]);
  float h = 0.f;
  for (int s = 0; s < SS; s++) {
    int cell = (s * BKT + bk) * CI + c;
    hin[cell * NN + n] = h;
    float ap = __expf(A * dsum[cell]);
    h = h * ap + hend[cell * NN + n];
  }
}

// ---------------- LayerNorm over CI + SiLU(z) gate (in-place on merged) ----------------
__global__ __launch_bounds__(192)
void k_lngate(float* __restrict__ merged,
              const float* __restrict__ z1, const float* __restrict__ z2,
              const float* __restrict__ n1w, const float* __restrict__ n1b,
              const float* __restrict__ n2w, const float* __restrict__ n2b) {
  int bid = blockIdx.x;
  int m = bid & 1;
  int bl = bid >> 1;
  int c = threadIdx.x;
  float v = merged[(size_t)bid * CI + c];
  float s1 = v, s2 = v * v;
  for (int o = 32; o > 0; o >>= 1) {
    s1 += __shfl_xor(s1, o);
    s2 += __shfl_xor(s2, o);
  }
  __shared__ float red[2][3];
  int wv = threadIdx.x >> 6, ln = threadIdx.x & 63;
  if (ln == 0) { red[0][wv] = s1; red[1][wv] = s2; }
  __syncthreads();
  float S1 = red[0][0] + red[0][1] + red[0][2];
  float S2 = red[1][0] + red[1][1] + red[1][2];
  float mean = S1 * (1.f / CI);
  float var = S2 * (1.f / CI) - mean * mean;
  float rstd = rsqrtf(var + 1e-5f);
  const float* nw = m ? n2w : n1w;
  const float* nb = m ? n2b : n1b;
  float vn = (v - mean) * rstd * nw[c] + nb[c];
  float z = (m ? z2 : z1)[(size_t)bl * CI + c];
  float g = vn * (z / (1.f + __expf(-z)));
  merged[(size_t)bid * CI + c] = g;
}

// ---------------- out_proj: LDS-tiled GEMM. M=16384, N=96, K=192 (2 chunks) ----------------
__global__ __launch_bounds__(256)
void k_outproj(const float* __restrict__ g,
               const float* __restrict__ w1, const float* __restrict__ w2,
               float* __restrict__ out) {
  int mb = blockIdx.x;
  int m  = blockIdx.y;
  const float* w = m ? w2 : w1;
  __shared__ float As[64][100];
  __shared__ float Ws[96][98];
  int t = threadIdx.x;
  int tc = t & 15, tr = t >> 4;
  float acc[4][6] = {};
  for (int kc = 0; kc < 2; kc++) {
    if (kc) __syncthreads();
    for (int i = t; i < 1536; i += 256) {
      int r = i / 24, kk = (i % 24) * 4;
      *(float4*)&As[r][kk] =
          *(const float4*)&g[((size_t)(mb * 64 + r) * 2 + m) * CI + kc * 96 + kk];
    }
    for (int i = t; i < 4608; i += 256) {
      int r = i / 48, kk = (i % 48) * 2;
      *(float2*)&Ws[r][kk] = *(const float2*)&w[(size_t)r * CI + kc * 96 + kk];
    }
    __syncthreads();
    for (int k = 0; k < 96; k += 2) {
      float2 a[4], b[6];
#pragma unroll
      for (int i = 0; i < 4; i++) a[i] = *(const float2*)&As[tr * 4 + i][k];
#pragma unroll
      for (int j = 0; j < 6; j++) b[j] = *(const float2*)&Ws[tc * 6 + j][k];
#pragma unroll
      for (int i = 0; i < 4; i++)
#pragma unroll
        for (int j = 0; j < 6; j++) {
          acc[i][j] = fmaf(a[i].x, b[j].x, acc[i][j]);
          acc[i][j] = fmaf(a[i].y, b[j].y, acc[i][j]);
        }
    }
  }
  float* outp = out + (size_t)m * (BB * LL * DM);
#pragma unroll
  for (int i = 0; i < 4; i++) {
    size_t bl = (size_t)mb * 64 + tr * 4 + i;
#pragma unroll
    for (int j = 0; j < 6; j++)
      outp[bl * DM + tc * 6 + j] = acc[i][j];
  }
}

extern "C" void kernel_launch(void* const* d_in, const int* in_sizes, int n_in,
                              void* d_out, int out_size, void* d_ws, size_t ws_size,
                              hipStream_t stream) {
  const float* rgb = (const float*)d_in[0];
  const float* tin = (const float*)d_in[1];
  const float* ip1 = (const float*)d_in[2];
  const float* ip2 = (const float*)d_in[3];
  const float* c1w = (const float*)d_in[4];
  const float* c1b = (const float*)d_in[5];
  const float* c2w = (const float*)d_in[6];
  const float* c2b = (const float*)d_in[7];
  const float* wx  = (const float*)d_in[8];
  const float* dtw = (const float*)d_in[9];
  const float* dtb = (const float*)d_in[10];
  const float* alg = (const float*)d_in[11];
  const float* Dsp = (const float*)d_in[12];
  const float* n1w = (const float*)d_in[13];
  const float* n1b = (const float*)d_in[14];
  const float* n2w = (const float*)d_in[15];
  const float* n2b = (const float*)d_in[16];
  const float* op1 = (const float*)d_in[17];
  const float* op2 = (const float*)d_in[18];

  float* ws = (float*)d_ws;
  float* xp1 = ws + OFF_XPRE1;
  float* xp2 = ws + OFF_XPRE2;
  float* z1  = ws + OFF_Z1;
  float* z2  = ws + OFF_Z2;
  float* x1c = ws + OFF_X1C;
  float* x2c = ws + OFF_X2C;
  float* dbl = ws + OFF_DBL;
  float* mg  = ws + OFF_MERG;
  float* dsm = ws + OFF_DSUM;
  // hend lives in the mg region (pass1 -> prop only; memset erases it afterwards).
  // hin spans xp1+xp2 (dead after k_conv): SS*BKT*CI*NN = 6291456 floats, exact fit.
  float* he  = ws + OFF_MERG;
  float* hi  = ws + OFF_XPRE1;
  float* out = (float*)d_out;

  k_inproj<<<dim3(256, 4, 2), 256, 0, stream>>>(rgb, tin, ip1, ip2, xp1, xp2, z1, z2);
  k_conv<<<dim3(12288, 2), 256, 0, stream>>>(xp1, xp2, c1w, c1b, c2w, c2b, x1c, x2c);
  k_dbl<<<dim3(128, 16), 256, 0, stream>>>(x1c, x2c, wx, dbl);
  k_scan<1><<<SS * BKT, 192, 0, stream>>>(x1c, x2c, dbl, dtw, dtb, alg, Dsp, he, dsm, hi, mg);
  k_prop<<<192, 256, 0, stream>>>(he, dsm, alg, hi);
  // zero the merge accumulator only now (hend is dead after k_prop)
  hipMemsetAsync(mg, 0, (size_t)6291456 * sizeof(float), stream);
  k_scan<2><<<SS * BKT, 192, 0, stream>>>(x1c, x2c, dbl, dtw, dtb, alg, Dsp, he, dsm, hi, mg);
  k_lngate<<<BB * LL * 2, 192, 0, stream>>>(mg, z1, z2, n1w, n1b, n2w, n2b);
  k_outproj<<<dim3(256, 2), 256, 0, stream>>>(mg, op1, op2, out);
}